// Round 3
// baseline (13389.427 us; speedup 1.0000x reference)
//
#include <hip/hip_runtime.h>

typedef unsigned short u16;
typedef unsigned int u32;
typedef unsigned long long u64;

#define BATCH 256
#define TT 512
#define HID 256
#define GATES 1024   // 4*HID
#define NEMB 512
#define VOC 27
#define HPAD 260     // 16B-aligned row, 260%32=4 -> 2-way LDS conflict (free)

__device__ __forceinline__ float bf1(u16 x){ union{u32 u; float f;} v; v.u = ((u32)x) << 16; return v.f; }
__device__ __forceinline__ u16 f2bf(float f){
  union{float f; u32 u;} v; v.f = f;
  u32 u = v.u;
  return (u16)((u + 0x7fffu + ((u >> 16) & 1u)) >> 16);
}
__device__ __forceinline__ float sigm(float x){ return 1.f / (1.f + __expf(-x)); }

// Sniff storage dtype of b_ih0 (1024 elems, |v| <= 1/16).
__global__ void k_detect(const u16* __restrict__ b, int* __restrict__ flag) {
  int bad = 0;
  for (int k = threadIdx.x; k < 512; k += 64)
    if (((b[2 * k] >> 7) & 0xFF) >= 127) bad = 1;
  unsigned long long m = __ballot(bad);   // single wave
  if (threadIdx.x == 0) flag[0] = (m != 0ULL) ? 0 : 1;
}

__global__ void k_convert(const void* __restrict__ src, float* __restrict__ dst,
                          int n, const int* __restrict__ flag) {
  int i = blockIdx.x * 256 + threadIdx.x;
  if (i >= n) return;
  dst[i] = flag[0] ? bf1(((const u16*)src)[i]) : ((const float*)src)[i];
}

// W0emb[v][g] = sum_i emb[v][i]*w_ih0[g][i] + b_ih0[g] + b_hh0[g]; emb row 26 := 0
__global__ void k_prep(const void* __restrict__ emb, const void* __restrict__ wih,
                       const void* __restrict__ bih, const void* __restrict__ bhh,
                       const int* __restrict__ flag, float* __restrict__ W0) {
  int idx = blockIdx.x * 256 + threadIdx.x;
  if (idx >= VOC * GATES) return;
  int v = idx >> 10, g = idx & (GATES - 1);
  int isbf = flag[0];
  float acc = isbf ? (bf1(((const u16*)bih)[g]) + bf1(((const u16*)bhh)[g]))
                   : (((const float*)bih)[g] + ((const float*)bhh)[g]);
  if (v != 26) {
    float s = 0.f;
    if (isbf) {
      const u16* e = (const u16*)emb + v * NEMB;
      const u16* w = (const u16*)wih + g * NEMB;
      for (int i = 0; i < NEMB; i++) s = fmaf(bf1(e[i]), bf1(w[i]), s);
    } else {
      const float* e = (const float*)emb + v * NEMB;
      const float* w = (const float*)wih + g * NEMB;
      for (int i = 0; i < NEMB; i++) s = fmaf(e[i], w[i], s);
    }
    acc += s;
  }
  W0[idx] = acc;
}

// Persistent fused 2-layer LSTM over all 512 timesteps.
// 256 blocks x 1024 threads, 1 block/CU (16 waves/CU = 4 waves/SIMD for latency hiding).
// Thread (rr = tid>>4 in [0,64), tb = tid&15): one gate row per thread per layer.
// Coherence protocol (NO release/acquire -> NO buffer_wbl2 / buffer_inv):
//   - h stores: relaxed AGENT atomic stores (write-through to coherence point)
//   - ordering: __syncthreads() drains vmcnt(0) before tid0 bumps cnt
//   - counter add + spin load + staging loads: relaxed AGENT (bypass L1/L2)
// Weights stay clean + resident in each XCD's L2.
__global__ __launch_bounds__(1024) void k_lstm(
    const int* __restrict__ ids, const float* __restrict__ W0,
    const float* __restrict__ whh0, const float* __restrict__ wih1,
    const float* __restrict__ whh1,
    const float* __restrict__ bih1, const float* __restrict__ bhh1,
    float* __restrict__ h0a, float* __restrict__ h0b,
    float* __restrict__ h1a, float* __restrict__ h1b,
    u32* __restrict__ bar)
{
  const int tid = threadIdx.x;
  const int bid = blockIdx.x;
  // cluster each bg-group on one XCD (bid%8 round-robin); correctness mapping-independent
  const int xcd = bid & 7, m = bid >> 3;
  const int bg = xcd * 2 + (m & 1);   // [0,16)
  const int jc = m >> 1;              // [0,16)

  const int tb = tid & 15;            // batch-in-group for GEMM phase
  const int rr = tid >> 4;            // row slot [0,64): gate = rr>>4, joff = rr&15
  const int grow = ((rr >> 4) << 8) + (jc << 4) + (rr & 15);

  __shared__ float hp0[16][HPAD];     // h0[t-1] tile: layer0 h-input AND layer1 x-input
  __shared__ float hp1[16][HPAD];     // h1[t-2] tile
  __shared__ float gs0[64][16];       // layer0 gates [row][b]
  __shared__ float gs1[64][16];       // layer1 gates
  __shared__ int   ids_s[16];

  const float* wl0 = whh0 + (size_t)grow * HID;
  const float* wi  = wih1 + (size_t)grow * HID;
  const float* wh  = whh1 + (size_t)grow * HID;
  const float bsum = bih1[grow] + bhh1[grow];

  // pointwise role (tid < 512): wave-uniform layer split; c-state in registers
  const int lay = tid >> 8;                 // waves 0-3: layer0, waves 4-7: layer1
  const int pb = tid & 15, pj = (tid >> 4) & 15;
  const int prow = (bg * 16 + pb) * HID + (jc * 16 + pj);
  float cr = 0.f;

  u32* cnt = bar + bg * 32;           // 128B-separated counters

  for (int t = 0; t <= TT; ++t) {
    const float* h0p = ((t + 1) & 1) ? h0b : h0a;  // h0[t-1]
    float*       h0n = (t & 1) ? h0b : h0a;        // h0[t]
    const float* h1p = (t & 1) ? h1b : h1a;        // h1[t-2]
    float*       h1n = ((t + 1) & 1) ? h1b : h1a;  // h1[t-1]

    // ---- stage prev h tiles (relaxed agent loads; coalesced, 2-way LDS banks) ----
    {
      const u64* s0base = (const u64*)(h0p + bg * 16 * HID);
      const u64* s1base = (const u64*)(h1p + bg * 16 * HID);
      #pragma unroll
      for (int u = 0; u < 2; ++u) {
        int e = tid + 1024 * u;         // u64 index into 16*128; lanes consecutive
        int sb = e >> 7, sk = e & 127;
        u64 v0 = __hip_atomic_load(s0base + e, __ATOMIC_RELAXED, __HIP_MEMORY_SCOPE_AGENT);
        u64 v1 = __hip_atomic_load(s1base + e, __ATOMIC_RELAXED, __HIP_MEMORY_SCOPE_AGENT);
        *(u64*)&hp0[sb][sk * 2] = v0;
        *(u64*)&hp1[sb][sk * 2] = v1;
      }
      if (t < TT && tid < 16) ids_s[tid] = ids[(bg * 16 + tid) * TT + t];
    }
    __syncthreads();

    // ---- layer0 gates, step t (one row per thread) ----
    if (t < TT) {
      float a = W0[(size_t)ids_s[tb] * GATES + grow];
      const float* hh = hp0[tb];
      #pragma unroll 8
      for (int k = 0; k < HID; k += 4) {
        float4 q = *(const float4*)(wl0 + k);
        float4 hv = *(const float4*)(hh + k);
        a = fmaf(q.x, hv.x, a); a = fmaf(q.y, hv.y, a);
        a = fmaf(q.z, hv.z, a); a = fmaf(q.w, hv.w, a);
      }
      gs0[rr][tb] = a;
    }

    // ---- layer1 gates, step t-1 (x = staged h0[t-1]); two independent chains ----
    if (t > 0) {
      float e0 = bsum, e1 = 0.f;
      const float* xx = hp0[tb];
      const float* hh = hp1[tb];
      #pragma unroll 8
      for (int k = 0; k < HID; k += 4) {
        float4 qi = *(const float4*)(wi + k);
        float4 qh = *(const float4*)(wh + k);
        float4 xv = *(const float4*)(xx + k);
        float4 hv = *(const float4*)(hh + k);
        e0 = fmaf(qi.x, xv.x, e0); e0 = fmaf(qi.y, xv.y, e0);
        e0 = fmaf(qi.z, xv.z, e0); e0 = fmaf(qi.w, xv.w, e0);
        e1 = fmaf(qh.x, hv.x, e1); e1 = fmaf(qh.y, hv.y, e1);
        e1 = fmaf(qh.z, hv.z, e1); e1 = fmaf(qh.w, hv.w, e1);
      }
      gs1[rr][tb] = e0 + e1;
    }
    __syncthreads();

    // ---- pointwise updates (c in registers), write-through h (no L2 dirty) ----
    if (tid < 512) {
      bool act = lay ? (t > 0) : (t < TT);
      if (act) {
        float (*gs)[16] = lay ? gs1 : gs0;
        float gi = sigm(gs[pj][pb]);
        float gf = sigm(gs[16 + pj][pb]);
        float gg = tanhf(gs[32 + pj][pb]);
        float go = sigm(gs[48 + pj][pb]);
        cr = fmaf(gf, cr, gi * gg);
        float* hn = lay ? h1n : h0n;
        __hip_atomic_store(&hn[prow], go * tanhf(cr),
                           __ATOMIC_RELAXED, __HIP_MEMORY_SCOPE_AGENT);
      }
    }

    // ---- group barrier (16 blocks sharing bg); no release fence needed:
    // __syncthreads drains vmcnt(0) -> h stores complete at coherence point
    if (t < TT) {
      __syncthreads();
      if (tid == 0) {
        __hip_atomic_fetch_add(cnt, 1u, __ATOMIC_RELAXED, __HIP_MEMORY_SCOPE_AGENT);
        u32 want = (u32)(16 * (t + 1));
        while (__hip_atomic_load(cnt, __ATOMIC_RELAXED, __HIP_MEMORY_SCOPE_AGENT) < want)
          __builtin_amdgcn_s_sleep(1);
      }
      __syncthreads();
    }
  }
}

// MLP head: out[b] = fc2_w . relu(fc1_w @ h[b] + fc1_b) + fc2_b
__global__ __launch_bounds__(128) void k_fc(
    const float* __restrict__ hfin,
    const void* __restrict__ fc1w, const void* __restrict__ fc1b,
    const void* __restrict__ fc2w, const void* __restrict__ fc2b,
    const int* __restrict__ flag, void* __restrict__ out) {
  int b = blockIdx.x, j = threadIdx.x;  // 128 threads
  __shared__ float red[128];
  const float* h = hfin + b * HID;
  int isbf = flag[0];
  float acc = isbf ? bf1(((const u16*)fc1b)[j]) : ((const float*)fc1b)[j];
  if (isbf) {
    const u16* w = (const u16*)fc1w + j * HID;
    for (int k = 0; k < HID; k++) acc = fmaf(bf1(w[k]), h[k], acc);
  } else {
    const float* w = (const float*)fc1w + j * HID;
    for (int k = 0; k < HID; k++) acc = fmaf(w[k], h[k], acc);
  }
  acc = fmaxf(acc, 0.f);
  float w2 = isbf ? bf1(((const u16*)fc2w)[j]) : ((const float*)fc2w)[j];
  red[j] = acc * w2;
  __syncthreads();
  for (int s = 64; s > 0; s >>= 1) {
    if (j < s) red[j] += red[j + s];
    __syncthreads();
  }
  if (j == 0) {
    float b2 = isbf ? bf1(((const u16*)fc2b)[0]) : ((const float*)fc2b)[0];
    float r = red[0] + b2;
    if (isbf) ((u16*)out)[b] = f2bf(r);
    else      ((float*)out)[b] = r;
  }
}

extern "C" void kernel_launch(void* const* d_in, const int* in_sizes, int n_in,
                              void* d_out, int out_size, void* d_ws, size_t ws_size,
                              hipStream_t stream) {
  const int* ids   = (const int*)d_in[0];
  const void* emb  = d_in[1];
  const void* wih0 = d_in[2];
  const void* whh0 = d_in[3];
  const void* bih0 = d_in[4];
  const void* bhh0 = d_in[5];
  const void* wih1 = d_in[6];
  const void* whh1 = d_in[7];
  const void* bih1 = d_in[8];
  const void* bhh1 = d_in[9];
  const void* fc1w = d_in[10];
  const void* fc1b = d_in[11];
  const void* fc2w = d_in[12];
  const void* fc2b = d_in[13];

  float* ws = (float*)d_ws;
  int*   flag    = (int*)ws;                  // 16-float pad
  float* W0emb   = ws + 16;                   // 27648
  float* whh0_f  = W0emb  + VOC * GATES;      // 262144
  float* wih1_f  = whh0_f + GATES * HID;      // 262144
  float* whh1_f  = wih1_f + GATES * HID;      // 262144
  float* bih1_f  = whh1_f + GATES * HID;      // 1024
  float* bhh1_f  = bih1_f + GATES;            // 1024
  float* h0A = bhh1_f + GATES;                // 65536 each below
  float* h0B = h0A + BATCH * HID;
  float* c0  = h0B + BATCH * HID;             // reused as barrier counters
  float* h1A = c0  + BATCH * HID;
  float* h1B = h1A + BATCH * HID;
  float* c1  = h1B + BATCH * HID;
  u32*   bar = (u32*)c0;                      // 16 groups x 32 u32 stride

  k_detect<<<1, 64, 0, stream>>>((const u16*)bih0, flag);

  k_convert<<<(GATES * HID + 255) / 256, 256, 0, stream>>>(whh0, whh0_f, GATES * HID, flag);
  k_convert<<<(GATES * HID + 255) / 256, 256, 0, stream>>>(wih1, wih1_f, GATES * HID, flag);
  k_convert<<<(GATES * HID + 255) / 256, 256, 0, stream>>>(whh1, whh1_f, GATES * HID, flag);
  k_convert<<<(GATES + 255) / 256, 256, 0, stream>>>(bih1, bih1_f, GATES, flag);
  k_convert<<<(GATES + 255) / 256, 256, 0, stream>>>(bhh1, bhh1_f, GATES, flag);

  // zero h0A,h0B,c0(=bar),h1A,h1B,c1 — also resets barrier counters each replay
  hipMemsetAsync(h0A, 0, (size_t)6 * BATCH * HID * sizeof(float), stream);

  k_prep<<<(VOC * GATES + 255) / 256, 256, 0, stream>>>(emb, wih0, bih0, bhh0, flag, W0emb);

  k_lstm<<<256, 1024, 0, stream>>>(ids, W0emb, whh0_f, wih1_f, whh1_f,
                                   bih1_f, bhh1_f, h0A, h0B, h1A, h1B, bar);

  // layer1 step 511 (iter t=512) wrote h1buf[1] = h1B
  k_fc<<<BATCH, 128, 0, stream>>>(h1B, fc1w, fc1b, fc2w, fc2b, flag, d_out);
}

// Round 4
// 13147.456 us; speedup vs baseline: 1.0184x; 1.0184x over previous
//
#include <hip/hip_runtime.h>

typedef unsigned short u16;
typedef unsigned int u32;
typedef unsigned long long u64;
typedef float f32x2 __attribute__((ext_vector_type(2)));

#define BATCH 256
#define TT 512
#define HID 256
#define GATES 1024   // 4*HID
#define NEMB 512
#define VOC 27
#define HPAD 260     // 1040B row: 16B aligned, 2-way LDS conflict max (free)

__device__ __forceinline__ float bf1(u16 x){ union{u32 u; float f;} v; v.u = ((u32)x) << 16; return v.f; }
__device__ __forceinline__ u16 f2bf(float f){
  union{float f; u32 u;} v; v.f = f;
  u32 u = v.u;
  return (u16)((u + 0x7fffu + ((u >> 16) & 1u)) >> 16);
}
__device__ __forceinline__ float sigm(float x){ return 1.f / (1.f + __expf(-x)); }
__device__ __forceinline__ f32x2 lo2(float4 v){ f32x2 r; r.x = v.x; r.y = v.y; return r; }
__device__ __forceinline__ f32x2 hi2(float4 v){ f32x2 r; r.x = v.z; r.y = v.w; return r; }

// Sniff storage dtype of b_ih0 (1024 elems, |v| <= 1/16).
__global__ void k_detect(const u16* __restrict__ b, int* __restrict__ flag) {
  int bad = 0;
  for (int k = threadIdx.x; k < 512; k += 64)
    if (((b[2 * k] >> 7) & 0xFF) >= 127) bad = 1;
  unsigned long long m = __ballot(bad);   // single wave
  if (threadIdx.x == 0) flag[0] = (m != 0ULL) ? 0 : 1;
}

__global__ void k_convert(const void* __restrict__ src, float* __restrict__ dst,
                          int n, const int* __restrict__ flag) {
  int i = blockIdx.x * 256 + threadIdx.x;
  if (i >= n) return;
  dst[i] = flag[0] ? bf1(((const u16*)src)[i]) : ((const float*)src)[i];
}

// W0emb[v][g] = sum_i emb[v][i]*w_ih0[g][i] + b_ih0[g] + b_hh0[g]; emb row 26 := 0
__global__ void k_prep(const void* __restrict__ emb, const void* __restrict__ wih,
                       const void* __restrict__ bih, const void* __restrict__ bhh,
                       const int* __restrict__ flag, float* __restrict__ W0) {
  int idx = blockIdx.x * 256 + threadIdx.x;
  if (idx >= VOC * GATES) return;
  int v = idx >> 10, g = idx & (GATES - 1);
  int isbf = flag[0];
  float acc = isbf ? (bf1(((const u16*)bih)[g]) + bf1(((const u16*)bhh)[g]))
                   : (((const float*)bih)[g] + ((const float*)bhh)[g]);
  if (v != 26) {
    float s = 0.f;
    if (isbf) {
      const u16* e = (const u16*)emb + v * NEMB;
      const u16* w = (const u16*)wih + g * NEMB;
      for (int i = 0; i < NEMB; i++) s = fmaf(bf1(e[i]), bf1(w[i]), s);
    } else {
      const float* e = (const float*)emb + v * NEMB;
      const float* w = (const float*)wih + g * NEMB;
      for (int i = 0; i < NEMB; i++) s = fmaf(e[i], w[i], s);
    }
    acc += s;
  }
  W0[idx] = acc;
}

// Persistent fused 2-layer LSTM, software-pipelined exchange.
// 256 blocks x 1024 threads, 1 block/CU. Block (bg,jc): 16 batches x 16 j.
// Skew: iter t computes L0 step t and L1 step t-2.
//   cnt0 publishes h0[t] BEFORE the L1 gemm -> barrier round trip overlaps L1 work.
//   cnt1 publishes h1[t-2]; consumers need it one full iteration later (slack).
// Coherence: relaxed AGENT atomics only (no wbl2/inv); __syncthreads drains
// vmcnt(0) before each arrive, so stores are at the coherence point.
__global__ __launch_bounds__(1024) void k_lstm(
    const int* __restrict__ ids, const float* __restrict__ W0,
    const float* __restrict__ whh0, const float* __restrict__ wih1,
    const float* __restrict__ whh1,
    const float* __restrict__ bih1, const float* __restrict__ bhh1,
    float* __restrict__ h0a, float* __restrict__ h0b,
    float* __restrict__ h1a, float* __restrict__ h1b,
    u32* __restrict__ bar)
{
  const int tid = threadIdx.x;
  const int bid = blockIdx.x;
  const int xcd = bid & 7, m = bid >> 3;
  const int bg = xcd * 2 + (m & 1);   // [0,16)
  const int jc = m >> 1;              // [0,16)

  const int tb = tid & 15;            // batch-in-group for GEMM phase
  const int rr = tid >> 4;            // row slot [0,64): gate = rr>>4, joff = rr&15
  const int grow = ((rr >> 4) << 8) + (jc << 4) + (rr & 15);

  __shared__ __align__(16) float hp0[2][16][HPAD]; // h0[t-1]/h0[t-2] tiles (double buf)
  __shared__ __align__(16) float hp1[16][HPAD];    // h1[t-3] tile
  __shared__ float gs0[64][17];       // layer0 gates [row][b], pad 17
  __shared__ float gs1[64][17];       // layer1 gates
  __shared__ int   ids_l[16][TT + 1]; // all ids for this bg, pad 513

  const float* wl0 = whh0 + (size_t)grow * HID;
  const float* wi  = wih1 + (size_t)grow * HID;
  const float* wh  = whh1 + (size_t)grow * HID;
  const float bsum = bih1[grow] + bhh1[grow];

  // pointwise role (tid < 256): cell (pb, pj); both layers' c-state in registers
  const int pj = tid & 15, pb = (tid >> 4) & 15;
  const int prow = (bg * 16 + pb) * HID + (jc * 16 + pj);
  float c0r = 0.f, c1r = 0.f;

  u32* cnt0 = bar + bg * 64;          // 256B-separated counter pairs
  u32* cnt1 = cnt0 + 32;

  // preload all ids for this batch group (coalesced, once)
  #pragma unroll
  for (int u = 0; u < 8; ++u) {
    int e = tid + 1024 * u;           // [0, 8192)
    int b = e >> 9, tt = e & 511;
    ids_l[b][tt] = ids[(bg * 16 + b) * TT + tt];
  }

  for (int t = 0; t <= TT + 1; ++t) {
    // ---- wait for group (tid0 spins; cnt1 has a full iter of slack) ----
    if (tid == 0) {
      if (t >= 1 && t <= TT) {
        u32 want = 16u * (u32)t;
        while (__hip_atomic_load(cnt0, __ATOMIC_RELAXED, __HIP_MEMORY_SCOPE_AGENT) < want)
          __builtin_amdgcn_s_sleep(1);
      }
      if (t >= 3) {
        u32 want = 16u * (u32)(t - 2);
        while (__hip_atomic_load(cnt1, __ATOMIC_RELAXED, __HIP_MEMORY_SCOPE_AGENT) < want)
          __builtin_amdgcn_s_sleep(1);
      }
    }
    __syncthreads();

    // ---- stage tiles (relaxed agent loads; coalesced; 2-way LDS banks) ----
    if (t <= TT) {
      const float* h0p = ((t + 1) & 1) ? h0b : h0a;      // h0[t-1]
      const u64* s0 = (const u64*)(h0p + bg * 16 * HID);
      float (*dst)[HPAD] = hp0[t & 1];
      #pragma unroll
      for (int u = 0; u < 2; ++u) {
        int e = tid + 1024 * u;
        u64 v = __hip_atomic_load(s0 + e, __ATOMIC_RELAXED, __HIP_MEMORY_SCOPE_AGENT);
        *(u64*)&dst[e >> 7][(e & 127) * 2] = v;
      }
    }
    if (t >= 2) {
      const float* h1p = ((t + 1) & 1) ? h1b : h1a;      // h1[t-3]
      const u64* s1 = (const u64*)(h1p + bg * 16 * HID);
      #pragma unroll
      for (int u = 0; u < 2; ++u) {
        int e = tid + 1024 * u;
        u64 v = __hip_atomic_load(s1 + e, __ATOMIC_RELAXED, __HIP_MEMORY_SCOPE_AGENT);
        *(u64*)&hp1[e >> 7][(e & 127) * 2] = v;
      }
    }
    __syncthreads();

    // ---- layer0 gates, step t (packed f32 -> v_pk_fma_f32) ----
    if (t < TT) {
      float xgv = W0[(size_t)ids_l[tb][t] * GATES + grow];
      const float4* w4 = (const float4*)wl0;
      const float4* h4 = (const float4*)hp0[t & 1][tb];
      f32x2 sA = {0.f, 0.f}, sB = {0.f, 0.f};
      #pragma unroll 8
      for (int k = 0; k < 64; ++k) {
        float4 q = w4[k], hv = h4[k];
        sA = lo2(q) * lo2(hv) + sA;
        sB = hi2(q) * hi2(hv) + sB;
      }
      gs0[rr][tb] = xgv + sA.x + sA.y + sB.x + sB.y;
    }
    __syncthreads();

    // ---- layer0 pointwise: store h0[t], then PUBLISH (overlaps with L1 below) ----
    if (t < TT && tid < 256) {
      float gi = sigm(gs0[pj][pb]);
      float gf = sigm(gs0[16 + pj][pb]);
      float gg = tanhf(gs0[32 + pj][pb]);
      float go = sigm(gs0[48 + pj][pb]);
      c0r = fmaf(gf, c0r, gi * gg);
      float* h0n = (t & 1) ? h0b : h0a;
      __hip_atomic_store(&h0n[prow], go * tanhf(c0r),
                         __ATOMIC_RELAXED, __HIP_MEMORY_SCOPE_AGENT);
    }
    __syncthreads();   // drains vmcnt(0): h0 stores at coherence point
    if (tid == 0 && t < TT)
      __hip_atomic_fetch_add(cnt0, 1u, __ATOMIC_RELAXED, __HIP_MEMORY_SCOPE_AGENT);

    // ---- layer1 gates, step t-2 (uses hp0 prev buffer + hp1; overlaps barrier) ----
    if (t >= 2) {
      const float4* wi4 = (const float4*)wi;
      const float4* wh4 = (const float4*)wh;
      const float4* x4  = (const float4*)hp0[(t - 1) & 1][tb];
      const float4* h4  = (const float4*)hp1[tb];
      f32x2 sIa = {0.f,0.f}, sIb = {0.f,0.f}, sHa = {0.f,0.f}, sHb = {0.f,0.f};
      #pragma unroll 8
      for (int k = 0; k < 64; ++k) {
        float4 qi = wi4[k], qh = wh4[k], xv = x4[k], hv = h4[k];
        sIa = lo2(qi) * lo2(xv) + sIa;
        sIb = hi2(qi) * hi2(xv) + sIb;
        sHa = lo2(qh) * lo2(hv) + sHa;
        sHb = hi2(qh) * hi2(hv) + sHb;
      }
      gs1[rr][tb] = bsum + sIa.x + sIa.y + sIb.x + sIb.y
                         + sHa.x + sHa.y + sHb.x + sHb.y;
    }
    __syncthreads();

    // ---- layer1 pointwise: store h1[t-2], publish cnt1 ----
    if (t >= 2 && tid < 256) {
      float gi = sigm(gs1[pj][pb]);
      float gf = sigm(gs1[16 + pj][pb]);
      float gg = tanhf(gs1[32 + pj][pb]);
      float go = sigm(gs1[48 + pj][pb]);
      c1r = fmaf(gf, c1r, gi * gg);
      float* h1n = (t & 1) ? h1b : h1a;   // parity of s = t-2
      __hip_atomic_store(&h1n[prow], go * tanhf(c1r),
                         __ATOMIC_RELAXED, __HIP_MEMORY_SCOPE_AGENT);
    }
    __syncthreads();   // drains vmcnt(0): h1 stores at coherence point
    if (tid == 0 && t >= 2 && t <= TT)
      __hip_atomic_fetch_add(cnt1, 1u, __ATOMIC_RELAXED, __HIP_MEMORY_SCOPE_AGENT);
  }
}

// MLP head: out[b] = fc2_w . relu(fc1_w @ h[b] + fc1_b) + fc2_b
__global__ __launch_bounds__(128) void k_fc(
    const float* __restrict__ hfin,
    const void* __restrict__ fc1w, const void* __restrict__ fc1b,
    const void* __restrict__ fc2w, const void* __restrict__ fc2b,
    const int* __restrict__ flag, void* __restrict__ out) {
  int b = blockIdx.x, j = threadIdx.x;  // 128 threads
  __shared__ float red[128];
  const float* h = hfin + b * HID;
  int isbf = flag[0];
  float acc = isbf ? bf1(((const u16*)fc1b)[j]) : ((const float*)fc1b)[j];
  if (isbf) {
    const u16* w = (const u16*)fc1w + j * HID;
    for (int k = 0; k < HID; k++) acc = fmaf(bf1(w[k]), h[k], acc);
  } else {
    const float* w = (const float*)fc1w + j * HID;
    for (int k = 0; k < HID; k++) acc = fmaf(w[k], h[k], acc);
  }
  acc = fmaxf(acc, 0.f);
  float w2 = isbf ? bf1(((const u16*)fc2w)[j]) : ((const float*)fc2w)[j];
  red[j] = acc * w2;
  __syncthreads();
  for (int s = 64; s > 0; s >>= 1) {
    if (j < s) red[j] += red[j + s];
    __syncthreads();
  }
  if (j == 0) {
    float b2 = isbf ? bf1(((const u16*)fc2b)[0]) : ((const float*)fc2b)[0];
    float r = red[0] + b2;
    if (isbf) ((u16*)out)[b] = f2bf(r);
    else      ((float*)out)[b] = r;
  }
}

extern "C" void kernel_launch(void* const* d_in, const int* in_sizes, int n_in,
                              void* d_out, int out_size, void* d_ws, size_t ws_size,
                              hipStream_t stream) {
  const int* ids   = (const int*)d_in[0];
  const void* emb  = d_in[1];
  const void* wih0 = d_in[2];
  const void* whh0 = d_in[3];
  const void* bih0 = d_in[4];
  const void* bhh0 = d_in[5];
  const void* wih1 = d_in[6];
  const void* whh1 = d_in[7];
  const void* bih1 = d_in[8];
  const void* bhh1 = d_in[9];
  const void* fc1w = d_in[10];
  const void* fc1b = d_in[11];
  const void* fc2w = d_in[12];
  const void* fc2b = d_in[13];

  float* ws = (float*)d_ws;
  int*   flag    = (int*)ws;                  // 16-float pad
  float* W0emb   = ws + 16;                   // 27648
  float* whh0_f  = W0emb  + VOC * GATES;      // 262144
  float* wih1_f  = whh0_f + GATES * HID;      // 262144
  float* whh1_f  = wih1_f + GATES * HID;      // 262144
  float* bih1_f  = whh1_f + GATES * HID;      // 1024
  float* bhh1_f  = bih1_f + GATES;            // 1024
  float* h0A = bhh1_f + GATES;                // 65536 each below
  float* h0B = h0A + BATCH * HID;
  float* c0  = h0B + BATCH * HID;             // reused as barrier counters
  float* h1A = c0  + BATCH * HID;
  float* h1B = h1A + BATCH * HID;
  float* c1  = h1B + BATCH * HID;
  u32*   bar = (u32*)c0;                      // 16 groups x (cnt0,cnt1) pairs, 256B apart

  k_detect<<<1, 64, 0, stream>>>((const u16*)bih0, flag);

  k_convert<<<(GATES * HID + 255) / 256, 256, 0, stream>>>(whh0, whh0_f, GATES * HID, flag);
  k_convert<<<(GATES * HID + 255) / 256, 256, 0, stream>>>(wih1, wih1_f, GATES * HID, flag);
  k_convert<<<(GATES * HID + 255) / 256, 256, 0, stream>>>(whh1, whh1_f, GATES * HID, flag);
  k_convert<<<(GATES + 255) / 256, 256, 0, stream>>>(bih1, bih1_f, GATES, flag);
  k_convert<<<(GATES + 255) / 256, 256, 0, stream>>>(bhh1, bhh1_f, GATES, flag);

  // zero h0A,h0B,c0(=bar),h1A,h1B,c1 — also resets barrier counters each replay
  hipMemsetAsync(h0A, 0, (size_t)6 * BATCH * HID * sizeof(float), stream);

  k_prep<<<(VOC * GATES + 255) / 256, 256, 0, stream>>>(emb, wih0, bih0, bhh0, flag, W0emb);

  k_lstm<<<256, 1024, 0, stream>>>(ids, W0emb, whh0_f, wih1_f, whh1_f,
                                   bih1_f, bhh1_f, h0A, h0B, h1A, h1B, bar);

  // L1 step 511 computed at iter t=513 (odd) -> stored into h1B
  k_fc<<<BATCH, 128, 0, stream>>>(h1B, fc1w, fc1b, fc2w, fc2b, flag, d_out);
}